// Round 1
// baseline (946.297 us; speedup 1.0000x reference)
//
#include <hip/hip_runtime.h>
#include <cstddef>
#include <cstdint>

#define N_IN  128
#define N_HID 128
#define N_OUT 64

// ---------------- CSR build ----------------

__global__ void count_deg_kernel(const int* __restrict__ ei, int* __restrict__ deg, int E) {
  int e = blockIdx.x * 256 + threadIdx.x;
  if (e < E) atomicAdd(&deg[ei[E + e]], 1);
}

__global__ __launch_bounds__(1024) void scan_kernel(const int* __restrict__ deg,
                                                    int* __restrict__ rowptr,
                                                    float* __restrict__ dis, int n) {
  __shared__ int sums[1024];
  int tid = threadIdx.x;
  int chunk = (n + 1023) >> 10;
  int start = tid * chunk;
  int end = min(start + chunk, n);
  int s = 0;
  for (int i = start; i < end; ++i) s += deg[i];
  sums[tid] = s;
  __syncthreads();
  for (int off = 1; off < 1024; off <<= 1) {
    int v = sums[tid];
    int o = (tid >= off) ? sums[tid - off] : 0;
    __syncthreads();
    sums[tid] = v + o;
    __syncthreads();
  }
  int prefix = (tid == 0) ? 0 : sums[tid - 1];
  for (int i = start; i < end; ++i) {
    rowptr[i] = prefix;
    int d = deg[i];
    dis[i] = (d > 0) ? rsqrtf((float)d) : 0.0f;
    prefix += d;
  }
  if (tid == 1023) rowptr[n] = sums[1023];
}

__global__ void fill_csr_kernel(const int* __restrict__ ei, int* __restrict__ cursor,
                                int* __restrict__ colidx, float* __restrict__ wv,
                                const float* __restrict__ dis, int E) {
  int e = blockIdx.x * 256 + threadIdx.x;
  if (e >= E) return;
  int s = ei[e];
  int d = ei[E + e];
  int pos = atomicAdd(&cursor[d], 1);
  colidx[pos] = s;
  wv[pos] = dis[s];
}

// ---------------- sparse propagation ----------------
// out[i] = -dis[i] * sum_e dis[src_e] * in[src_e]          (sub == nullptr)
// out[i] = 2*(-dis[i] * sum) - sub[i]                      (sub != nullptr)
// one wave (64 lanes) per node, float2 per lane over the 128-wide row

__global__ __launch_bounds__(256) void prop_kernel(
    const float* __restrict__ in, const float* __restrict__ sub,
    float* __restrict__ out, const int* __restrict__ rowptr,
    const int* __restrict__ colidx, const float* __restrict__ wv,
    const float* __restrict__ dis, int n) {
  int node = blockIdx.x * 4 + (threadIdx.x >> 6);
  if (node >= n) return;
  int lane = threadIdx.x & 63;
  int start = rowptr[node];
  int end = rowptr[node + 1];
  float ax = 0.f, ay = 0.f;
  for (int e = start; e < end; ++e) {
    int c = colidx[e];
    float w = wv[e];
    const float2 v = *reinterpret_cast<const float2*>(in + ((size_t)c << 7) + (lane << 1));
    ax = fmaf(w, v.x, ax);
    ay = fmaf(w, v.y, ay);
  }
  float scale = -dis[node];
  size_t ro = ((size_t)node << 7) + (lane << 1);
  float2 r;
  if (sub != nullptr) {
    const float2 sv = *reinterpret_cast<const float2*>(sub + ro);
    r.x = fmaf(2.f * scale, ax, -sv.x);
    r.y = fmaf(2.f * scale, ay, -sv.y);
  } else {
    r.x = scale * ax;
    r.y = scale * ay;
  }
  *reinterpret_cast<float2*>(out + ro) = r;
}

// ---------------- fused Chebyshev GEMM ----------------
// out = (relu?)( A0@W[0] + A1@W[1] + A2@W[2] + A3@W[3] + bias )
// A*: [n,128] f32. W: [4][128][FOUT]. 64-row tile, 256 threads,
// each thread: RPT rows x 4 cols register block; A tile + 32-row W chunk in LDS.

template <int FOUT, bool RELU>
__global__ __launch_bounds__(256) void cheb_gemm_kernel(
    const float* __restrict__ A0, const float* __restrict__ A1,
    const float* __restrict__ A2, const float* __restrict__ A3,
    const float* __restrict__ W, const float* __restrict__ bias,
    float* __restrict__ out, int n) {
  constexpr int BM = 64;
  constexpr int CG = FOUT / 4;   // col groups of 4
  constexpr int RG = 256 / CG;   // row groups
  constexpr int RPT = BM / RG;   // rows per thread
  __shared__ float As[BM][N_IN];
  __shared__ float Ws[32][FOUT];
  const float* Ap[4] = {A0, A1, A2, A3};
  int tid = threadIdx.x;
  int row0 = blockIdx.x * BM;
  int cg = tid % CG, rg = tid / CG;
  int c0 = cg * 4;
  float acc[RPT][4];
#pragma unroll
  for (int i = 0; i < RPT; ++i) {
    acc[i][0] = acc[i][1] = acc[i][2] = acc[i][3] = 0.f;
  }

  for (int k = 0; k < 4; ++k) {
    __syncthreads();
    const float* A = Ap[k];
    for (int t = tid; t < BM * (N_IN / 4); t += 256) {
      int r = t >> 5;      // 32 float4 per row
      int q = t & 31;
      int grow = row0 + r;
      float4 v = make_float4(0.f, 0.f, 0.f, 0.f);
      if (grow < n) v = reinterpret_cast<const float4*>(A + ((size_t)grow << 7))[q];
      reinterpret_cast<float4*>(&As[r][0])[q] = v;
    }
    const float* Wk = W + (size_t)k * N_IN * FOUT;
    for (int kc = 0; kc < N_IN; kc += 32) {
      __syncthreads();
      const float4* Wsrc = reinterpret_cast<const float4*>(Wk + kc * FOUT);
      for (int t = tid; t < 32 * FOUT / 4; t += 256)
        reinterpret_cast<float4*>(&Ws[0][0])[t] = Wsrc[t];
      __syncthreads();
#pragma unroll
      for (int kk = 0; kk < 32; ++kk) {
        float4 w = *reinterpret_cast<const float4*>(&Ws[kk][c0]);
#pragma unroll
        for (int i = 0; i < RPT; ++i) {
          float a = As[rg + i * RG][kk + kc];
          acc[i][0] = fmaf(a, w.x, acc[i][0]);
          acc[i][1] = fmaf(a, w.y, acc[i][1]);
          acc[i][2] = fmaf(a, w.z, acc[i][2]);
          acc[i][3] = fmaf(a, w.w, acc[i][3]);
        }
      }
    }
  }
  float4 bv = *reinterpret_cast<const float4*>(bias + c0);
#pragma unroll
  for (int i = 0; i < RPT; ++i) {
    int grow = row0 + rg + i * RG;
    if (grow >= n) continue;
    float4 o;
    o.x = acc[i][0] + bv.x;
    o.y = acc[i][1] + bv.y;
    o.z = acc[i][2] + bv.z;
    o.w = acc[i][3] + bv.w;
    if (RELU) {
      o.x = fmaxf(o.x, 0.f); o.y = fmaxf(o.y, 0.f);
      o.z = fmaxf(o.z, 0.f); o.w = fmaxf(o.w, 0.f);
    }
    reinterpret_cast<float4*>(out + (size_t)grow * FOUT)[cg] = o;
  }
}

// ---------------- row log-softmax (64 cols, one wave per row) ----------------

__global__ __launch_bounds__(256) void log_softmax_kernel(float* __restrict__ io, int n) {
  int row = blockIdx.x * 4 + (threadIdx.x >> 6);
  if (row >= n) return;
  int lane = threadIdx.x & 63;
  size_t idx = (size_t)row * 64 + lane;
  float v = io[idx];
  float m = v;
#pragma unroll
  for (int off = 32; off > 0; off >>= 1) m = fmaxf(m, __shfl_xor(m, off, 64));
  float ex = expf(v - m);
  float s = ex;
#pragma unroll
  for (int off = 32; off > 0; off >>= 1) s += __shfl_xor(s, off, 64);
  io[idx] = (v - m) - logf(s);
}

// ---------------- launcher ----------------

extern "C" void kernel_launch(void* const* d_in, const int* in_sizes, int n_in,
                              void* d_out, int out_size, void* d_ws, size_t ws_size,
                              hipStream_t stream) {
  const float* x  = (const float*)d_in[0];
  const int*   ei = (const int*)d_in[1];
  const float* W1 = (const float*)d_in[2];
  const float* b1 = (const float*)d_in[3];
  const float* W2 = (const float*)d_in[4];
  const float* b2 = (const float*)d_in[5];
  float* out = (float*)d_out;

  const int N = in_sizes[0] / N_IN;
  const int E = in_sizes[1] / 2;

  char* base = (char*)d_ws;
  size_t off = 0;
  auto alloc = [&](size_t bytes) -> void* {
    void* p = base + off;
    off = (off + bytes + 255) & ~(size_t)255;
    return p;
  };
  int*   deg    = (int*)alloc((size_t)N * 4);
  int*   rowptr = (int*)alloc((size_t)(N + 1) * 4);
  int*   cursor = (int*)alloc((size_t)N * 4);
  int*   colidx = (int*)alloc((size_t)E * 4);
  float* wv     = (float*)alloc((size_t)E * 4);
  float* dis    = (float*)alloc((size_t)N * 4);
  float* T1     = (float*)alloc((size_t)N * N_IN * 4);
  float* T2     = (float*)alloc((size_t)N * N_IN * 4);
  float* T3     = (float*)alloc((size_t)N * N_IN * 4);
  float* H      = (float*)alloc((size_t)N * N_IN * 4);

  hipMemsetAsync(deg, 0, (size_t)N * 4, stream);
  count_deg_kernel<<<(E + 255) / 256, 256, 0, stream>>>(ei, deg, E);
  scan_kernel<<<1, 1024, 0, stream>>>(deg, rowptr, dis, N);
  hipMemcpyAsync(cursor, rowptr, (size_t)N * 4, hipMemcpyDeviceToDevice, stream);
  fill_csr_kernel<<<(E + 255) / 256, 256, 0, stream>>>(ei, cursor, colidx, wv, dis, E);

  int pgrid = (N + 3) / 4;
  // layer 1: Tx0 = x
  prop_kernel<<<pgrid, 256, 0, stream>>>(x,  nullptr, T1, rowptr, colidx, wv, dis, N);
  prop_kernel<<<pgrid, 256, 0, stream>>>(T1, x,       T2, rowptr, colidx, wv, dis, N);
  prop_kernel<<<pgrid, 256, 0, stream>>>(T2, T1,      T3, rowptr, colidx, wv, dis, N);
  cheb_gemm_kernel<N_HID, true><<<(N + 63) / 64, 256, 0, stream>>>(x, T1, T2, T3, W1, b1, H, N);
  // layer 2: Tx0 = H
  prop_kernel<<<pgrid, 256, 0, stream>>>(H,  nullptr, T1, rowptr, colidx, wv, dis, N);
  prop_kernel<<<pgrid, 256, 0, stream>>>(T1, H,       T2, rowptr, colidx, wv, dis, N);
  prop_kernel<<<pgrid, 256, 0, stream>>>(T2, T1,      T3, rowptr, colidx, wv, dis, N);
  cheb_gemm_kernel<N_OUT, false><<<(N + 63) / 64, 256, 0, stream>>>(H, T1, T2, T3, W2, b2, out, N);

  log_softmax_kernel<<<(N + 3) / 4, 256, 0, stream>>>(out, N);
}

// Round 2
// 749.481 us; speedup vs baseline: 1.2626x; 1.2626x over previous
//
#include <hip/hip_runtime.h>
#include <cstddef>
#include <cstdint>

#define N_IN  128
#define N_HID 128
#define N_OUT 64

typedef unsigned short ushort;
typedef unsigned int uint;
using short8 = __attribute__((ext_vector_type(8))) short;
using f32x4  = __attribute__((ext_vector_type(4))) float;

__device__ __forceinline__ ushort f2b(float f) {
  uint u = __builtin_bit_cast(uint, f);
  uint r = (u + 0x7fffu + ((u >> 16) & 1u)) >> 16;   // RNE
  return (ushort)r;
}
__device__ __forceinline__ float b2f(ushort u) {
  return __builtin_bit_cast(float, ((uint)u) << 16);
}

// ---------------- CSR build ----------------

__global__ void count_deg_kernel(const int* __restrict__ ei, int* __restrict__ deg, int E) {
  int e = blockIdx.x * 256 + threadIdx.x;
  if (e < E) atomicAdd(&deg[ei[E + e]], 1);
}

__global__ __launch_bounds__(1024) void scan_kernel(const int* __restrict__ deg,
                                                    int* __restrict__ rowptr,
                                                    float* __restrict__ dis, int n) {
  __shared__ int sums[1024];
  int tid = threadIdx.x;
  int chunk = (n + 1023) >> 10;
  int start = tid * chunk;
  int end = min(start + chunk, n);
  int s = 0;
  for (int i = start; i < end; ++i) s += deg[i];
  sums[tid] = s;
  __syncthreads();
  for (int off = 1; off < 1024; off <<= 1) {
    int v = sums[tid];
    int o = (tid >= off) ? sums[tid - off] : 0;
    __syncthreads();
    sums[tid] = v + o;
    __syncthreads();
  }
  int prefix = (tid == 0) ? 0 : sums[tid - 1];
  for (int i = start; i < end; ++i) {
    rowptr[i] = prefix;
    int d = deg[i];
    dis[i] = (d > 0) ? rsqrtf((float)d) : 0.0f;
    prefix += d;
  }
  if (tid == 1023) rowptr[n] = sums[1023];
}

__global__ void fill_csr_kernel(const int* __restrict__ ei, int* __restrict__ cursor,
                                int2* __restrict__ ew, const float* __restrict__ dis, int E) {
  int e = blockIdx.x * 256 + threadIdx.x;
  if (e >= E) return;
  int s = ei[e];
  int d = ei[E + e];
  int pos = atomicAdd(&cursor[d], 1);
  ew[pos] = make_int2(s, __builtin_bit_cast(int, dis[s]));
}

// ---------------- fp32 -> bf16 convert ----------------

__global__ __launch_bounds__(256) void cvt_bf16_kernel(const float* __restrict__ in,
                                                       ushort* __restrict__ out, int n4) {
  int i = blockIdx.x * 256 + threadIdx.x;
  if (i >= n4) return;
  float4 v = reinterpret_cast<const float4*>(in)[i];
  ushort4 o;
  o.x = f2b(v.x); o.y = f2b(v.y); o.z = f2b(v.z); o.w = f2b(v.w);
  reinterpret_cast<ushort4*>(out)[i] = o;
}

// ---------------- W pack into MFMA B-fragment order ----------------
// pw[(k*4+kk)*CT + ct][lane][j] = W[k][kk*32 + (lane>>4)*8 + j][ct*16 + (lane&15)]

template <int FOUT>
__global__ __launch_bounds__(256) void pack_w_kernel(const float* __restrict__ W,
                                                     ushort* __restrict__ pw) {
  constexpr int CT = FOUT / 16;
  int t = blockIdx.x * 256 + threadIdx.x;
  if (t >= 4 * 4 * CT * 64) return;
  int lane = t & 63;
  int g = t >> 6;
  int ct = g % CT;
  int kk = (g / CT) % 4;
  int k  = g / (CT * 4);
  int col = ct * 16 + (lane & 15);
  int krow0 = kk * 32 + (lane >> 4) * 8;
  ushort* dst = pw + (size_t)t * 8;
  const float* src = W + ((size_t)k * 128 + krow0) * FOUT + col;
#pragma unroll
  for (int j = 0; j < 8; ++j) dst[j] = f2b(src[(size_t)j * FOUT]);
}

// ---------------- sparse propagation (bf16 in/out, fp32 accumulate) ----------------
// out[i] = -dis[i] * sum_e dis[src]*in[src]         (sub==nullptr)
// out[i] = 2*(-dis[i]*sum) - sub[i]                 (sub!=nullptr)

__global__ __launch_bounds__(256) void prop_kernel(
    const ushort* __restrict__ in, const ushort* __restrict__ sub,
    ushort* __restrict__ out, const int* __restrict__ rowptr,
    const int2* __restrict__ ew, const float* __restrict__ dis, int n) {
  int node = blockIdx.x * 4 + (threadIdx.x >> 6);
  if (node >= n) return;
  int lane = threadIdx.x & 63;
  int s = rowptr[node];
  int e = rowptr[node + 1];
  float ax = 0.f, ay = 0.f;
  for (int i = s; i < e; ++i) {
    int2 p = ew[i];
    float w = __builtin_bit_cast(float, p.y);
    uint v = *reinterpret_cast<const uint*>(in + ((size_t)p.x << 7) + (lane << 1));
    ax = fmaf(w, b2f((ushort)v), ax);
    ay = fmaf(w, b2f((ushort)(v >> 16)), ay);
  }
  float sc = -dis[node];
  size_t ro = ((size_t)node << 7) + (lane << 1);
  float rx, ry;
  if (sub != nullptr) {
    uint sv = *reinterpret_cast<const uint*>(sub + ro);
    rx = fmaf(2.f * sc, ax, -b2f((ushort)sv));
    ry = fmaf(2.f * sc, ay, -b2f((ushort)(sv >> 16)));
  } else {
    rx = sc * ax;
    ry = sc * ay;
  }
  *reinterpret_cast<uint*>(out + ro) = (uint)f2b(rx) | ((uint)f2b(ry) << 16);
}

// ---------------- MFMA Chebyshev GEMM ----------------
// out = (relu?)( [A0|A1|A2|A3] @ packedW + bias ), A*: [n,128] bf16.
// One wave per 16 rows, no LDS. A-frag: lane reads A[row0+(lane&15)][(lane>>4)*8 + ...].
// D mapping (m89-verified): col = lane&15, row = (lane>>4)*4 + reg.

template <int FOUT, bool RELU, bool OUT_BF16>
__global__ __launch_bounds__(256) void mfma_gemm_kernel(
    const ushort* __restrict__ A0, const ushort* __restrict__ A1,
    const ushort* __restrict__ A2, const ushort* __restrict__ A3,
    const ushort* __restrict__ pw, const float* __restrict__ bias,
    void* __restrict__ outv, int n) {
  constexpr int CT = FOUT / 16;
  int wid = threadIdx.x >> 6;
  int lane = threadIdx.x & 63;
  int row0 = (blockIdx.x * 4 + wid) * 16;
  if (row0 >= n) return;   // n % 16 == 0 for this problem
  const ushort* Ap[4] = {A0, A1, A2, A3};
  f32x4 acc[CT];
#pragma unroll
  for (int c = 0; c < CT; ++c) acc[c] = (f32x4){0.f, 0.f, 0.f, 0.f};
  size_t aoff = (size_t)(row0 + (lane & 15)) * 128 + (lane >> 4) * 8;
#pragma unroll
  for (int k = 0; k < 4; ++k) {
    const ushort* A = Ap[k] + aoff;
#pragma unroll
    for (int kk = 0; kk < 4; ++kk) {
      short8 a = *reinterpret_cast<const short8*>(A + kk * 32);
      const ushort* B = pw + ((size_t)((k * 4 + kk) * CT) * 64 + lane) * 8;
#pragma unroll
      for (int c = 0; c < CT; ++c) {
        short8 b = *reinterpret_cast<const short8*>(B + (size_t)c * 64 * 8);
        acc[c] = __builtin_amdgcn_mfma_f32_16x16x32_bf16(a, b, acc[c], 0, 0, 0);
      }
    }
  }
  int colb = lane & 15;
  int rsub = (lane >> 4) * 4;
#pragma unroll
  for (int c = 0; c < CT; ++c) {
    int col = c * 16 + colb;
    float bv = bias[col];
#pragma unroll
    for (int r = 0; r < 4; ++r) {
      float v = acc[c][r] + bv;
      if (RELU) v = fmaxf(v, 0.f);
      size_t oi = (size_t)(row0 + rsub + r) * FOUT + col;
      if (OUT_BF16) reinterpret_cast<ushort*>(outv)[oi] = f2b(v);
      else          reinterpret_cast<float*>(outv)[oi] = v;
    }
  }
}

// ---------------- row log-softmax (64 cols, one wave per row) ----------------

__global__ __launch_bounds__(256) void log_softmax_kernel(float* __restrict__ io, int n) {
  int row = blockIdx.x * 4 + (threadIdx.x >> 6);
  if (row >= n) return;
  int lane = threadIdx.x & 63;
  size_t idx = (size_t)row * 64 + lane;
  float v = io[idx];
  float m = v;
#pragma unroll
  for (int off = 32; off > 0; off >>= 1) m = fmaxf(m, __shfl_xor(m, off, 64));
  float ex = expf(v - m);
  float s = ex;
#pragma unroll
  for (int off = 32; off > 0; off >>= 1) s += __shfl_xor(s, off, 64);
  io[idx] = (v - m) - logf(s);
}

// ---------------- launcher ----------------

extern "C" void kernel_launch(void* const* d_in, const int* in_sizes, int n_in,
                              void* d_out, int out_size, void* d_ws, size_t ws_size,
                              hipStream_t stream) {
  const float* x  = (const float*)d_in[0];
  const int*   ei = (const int*)d_in[1];
  const float* W1 = (const float*)d_in[2];
  const float* b1 = (const float*)d_in[3];
  const float* W2 = (const float*)d_in[4];
  const float* b2 = (const float*)d_in[5];
  float* out = (float*)d_out;

  const int N = in_sizes[0] / N_IN;
  const int E = in_sizes[1] / 2;

  char* base = (char*)d_ws;
  size_t off = 0;
  auto alloc = [&](size_t bytes) -> void* {
    void* p = base + off;
    off = (off + bytes + 255) & ~(size_t)255;
    return p;
  };
  int*    deg    = (int*)alloc((size_t)N * 4);
  int*    rowptr = (int*)alloc((size_t)(N + 1) * 4);
  int*    cursor = (int*)alloc((size_t)N * 4);
  int2*   ew     = (int2*)alloc((size_t)E * 8);
  float*  dis    = (float*)alloc((size_t)N * 4);
  ushort* xb     = (ushort*)alloc((size_t)N * N_IN * 2);
  ushort* T1     = (ushort*)alloc((size_t)N * N_IN * 2);
  ushort* T2     = (ushort*)alloc((size_t)N * N_IN * 2);
  ushort* T3     = (ushort*)alloc((size_t)N * N_IN * 2);
  ushort* H      = (ushort*)alloc((size_t)N * N_IN * 2);
  ushort* pw1    = (ushort*)alloc((size_t)4 * N_IN * N_HID * 2);
  ushort* pw2    = (ushort*)alloc((size_t)4 * N_HID * N_OUT * 2);

  hipMemsetAsync(deg, 0, (size_t)N * 4, stream);
  count_deg_kernel<<<(E + 255) / 256, 256, 0, stream>>>(ei, deg, E);
  scan_kernel<<<1, 1024, 0, stream>>>(deg, rowptr, dis, N);
  hipMemcpyAsync(cursor, rowptr, (size_t)N * 4, hipMemcpyDeviceToDevice, stream);
  fill_csr_kernel<<<(E + 255) / 256, 256, 0, stream>>>(ei, cursor, ew, dis, E);

  int n4 = N * N_IN / 4;
  cvt_bf16_kernel<<<(n4 + 255) / 256, 256, 0, stream>>>(x, xb, n4);
  pack_w_kernel<N_HID><<<(4 * 4 * (N_HID / 16) * 64 + 255) / 256, 256, 0, stream>>>(W1, pw1);
  pack_w_kernel<N_OUT><<<(4 * 4 * (N_OUT / 16) * 64 + 255) / 256, 256, 0, stream>>>(W2, pw2);

  int pgrid = (N + 3) / 4;
  int ggrid = (N + 63) / 64;
  // layer 1: Tx0 = xb
  prop_kernel<<<pgrid, 256, 0, stream>>>(xb, nullptr, T1, rowptr, ew, dis, N);
  prop_kernel<<<pgrid, 256, 0, stream>>>(T1, xb,      T2, rowptr, ew, dis, N);
  prop_kernel<<<pgrid, 256, 0, stream>>>(T2, T1,      T3, rowptr, ew, dis, N);
  mfma_gemm_kernel<N_HID, true, true><<<ggrid, 256, 0, stream>>>(xb, T1, T2, T3, pw1, b1, H, N);
  // layer 2: Tx0 = H
  prop_kernel<<<pgrid, 256, 0, stream>>>(H,  nullptr, T1, rowptr, ew, dis, N);
  prop_kernel<<<pgrid, 256, 0, stream>>>(T1, H,       T2, rowptr, ew, dis, N);
  prop_kernel<<<pgrid, 256, 0, stream>>>(T2, T1,      T3, rowptr, ew, dis, N);
  mfma_gemm_kernel<N_OUT, false, false><<<ggrid, 256, 0, stream>>>(H, T1, T2, T3, pw2, b2, out, N);

  log_softmax_kernel<<<(N + 3) / 4, 256, 0, stream>>>(out, N);
}

// Round 3
// 407.345 us; speedup vs baseline: 2.3231x; 1.8399x over previous
//
#include <hip/hip_runtime.h>
#include <cstddef>
#include <cstdint>

#define N_IN  128
#define N_HID 128
#define N_OUT 64

typedef unsigned short ushort;
typedef unsigned int uint;
using short8 = __attribute__((ext_vector_type(8))) short;
using f32x4  = __attribute__((ext_vector_type(4))) float;

__device__ __forceinline__ ushort f2b(float f) {
  uint u = __builtin_bit_cast(uint, f);
  uint r = (u + 0x7fffu + ((u >> 16) & 1u)) >> 16;   // RNE
  return (ushort)r;
}
__device__ __forceinline__ float b2f(ushort u) {
  return __builtin_bit_cast(float, ((uint)u) << 16);
}

// ---------------- CSR build ----------------

__global__ void count_deg_kernel(const int* __restrict__ ei, int* __restrict__ deg, int E) {
  int e = blockIdx.x * 256 + threadIdx.x;
  if (e < E) atomicAdd(&deg[ei[E + e]], 1);
}

// hierarchical scan: A) per-block sums  B) scan of block sums  C) final rowptr+dis

__global__ __launch_bounds__(256) void scanA_kernel(const int* __restrict__ deg,
                                                    int* __restrict__ bsum, int n) {
  int i = blockIdx.x * 256 + threadIdx.x;
  int v = (i < n) ? deg[i] : 0;
#pragma unroll
  for (int off = 32; off > 0; off >>= 1) v += __shfl_xor(v, off, 64);
  __shared__ int ws[4];
  int lane = threadIdx.x & 63, wid = threadIdx.x >> 6;
  if (lane == 0) ws[wid] = v;
  __syncthreads();
  if (threadIdx.x == 0) bsum[blockIdx.x] = ws[0] + ws[1] + ws[2] + ws[3];
}

__global__ __launch_bounds__(256) void scanB_kernel(int* __restrict__ bsum, int nb) {
  int tid = threadIdx.x;
  int c = (nb + 255) >> 8;
  int st = tid * c, en = min(st + c, nb);
  int s = 0;
  for (int i = st; i < en; ++i) s += bsum[i];
  int lane = tid & 63, wid = tid >> 6;
  int incl = s;
#pragma unroll
  for (int off = 1; off < 64; off <<= 1) {
    int t = __shfl_up(incl, off, 64);
    if (lane >= off) incl += t;
  }
  __shared__ int ws[4];
  if (lane == 63) ws[wid] = incl;
  __syncthreads();
  int wbase = 0;
  for (int w = 0; w < wid; ++w) wbase += ws[w];
  int ex = wbase + incl - s;
  for (int i = st; i < en; ++i) {
    int d = bsum[i];
    bsum[i] = ex;
    ex += d;
  }
}

__global__ __launch_bounds__(256) void scanC_kernel(const int* __restrict__ deg,
                                                    const int* __restrict__ bsum,
                                                    int* __restrict__ rowptr,
                                                    float* __restrict__ dis, int n) {
  int i = blockIdx.x * 256 + threadIdx.x;
  int d = (i < n) ? deg[i] : 0;
  int lane = threadIdx.x & 63, wid = threadIdx.x >> 6;
  int incl = d;
#pragma unroll
  for (int off = 1; off < 64; off <<= 1) {
    int t = __shfl_up(incl, off, 64);
    if (lane >= off) incl += t;
  }
  __shared__ int ws[4];
  if (lane == 63) ws[wid] = incl;
  __syncthreads();
  int wbase = 0;
  for (int w = 0; w < wid; ++w) wbase += ws[w];
  int ex = bsum[blockIdx.x] + wbase + incl - d;
  if (i < n) {
    rowptr[i] = ex;
    dis[i] = (d > 0) ? rsqrtf((float)d) : 0.0f;
    if (i == n - 1) rowptr[n] = ex + d;
  }
}

__global__ void fill_csr_kernel(const int* __restrict__ ei, int* __restrict__ cursor,
                                int2* __restrict__ ew, const float* __restrict__ dis, int E) {
  int e = blockIdx.x * 256 + threadIdx.x;
  if (e >= E) return;
  int s = ei[e];
  int d = ei[E + e];
  int pos = atomicAdd(&cursor[d], 1);
  ew[pos] = make_int2(s, __builtin_bit_cast(int, dis[s]));
}

// ---------------- fp32 -> bf16 convert ----------------

__global__ __launch_bounds__(256) void cvt_bf16_kernel(const float* __restrict__ in,
                                                       ushort* __restrict__ out, int n4) {
  int i = blockIdx.x * 256 + threadIdx.x;
  if (i >= n4) return;
  float4 v = reinterpret_cast<const float4*>(in)[i];
  ushort4 o;
  o.x = f2b(v.x); o.y = f2b(v.y); o.z = f2b(v.z); o.w = f2b(v.w);
  reinterpret_cast<ushort4*>(out)[i] = o;
}

// ---------------- W pack into MFMA B-fragment order ----------------
// pw[(k*4+kk)*CT + ct][lane][j] = W[k][kk*32 + (lane>>4)*8 + j][ct*16 + (lane&15)]

template <int FOUT>
__global__ __launch_bounds__(256) void pack_w_kernel(const float* __restrict__ W,
                                                     ushort* __restrict__ pw) {
  constexpr int CT = FOUT / 16;
  int t = blockIdx.x * 256 + threadIdx.x;
  if (t >= 4 * 4 * CT * 64) return;
  int lane = t & 63;
  int g = t >> 6;
  int ct = g % CT;
  int kk = (g / CT) % 4;
  int k  = g / (CT * 4);
  int col = ct * 16 + (lane & 15);
  int krow0 = kk * 32 + (lane >> 4) * 8;
  ushort* dst = pw + (size_t)t * 8;
  const float* src = W + ((size_t)k * 128 + krow0) * FOUT + col;
#pragma unroll
  for (int j = 0; j < 8; ++j) dst[j] = f2b(src[(size_t)j * FOUT]);
}

// ---------------- sparse propagation (bf16 in/out, fp32 accumulate) ----------------
// out[i] = -dis[i] * sum_e dis[src]*in[src]         (sub==nullptr)
// out[i] = 2*(-dis[i]*sum) - sub[i]                 (sub!=nullptr)
// one wave per node; edge loop unrolled x4 for 4 outstanding 256B gathers

__global__ __launch_bounds__(256) void prop_kernel(
    const ushort* __restrict__ in, const ushort* __restrict__ sub,
    ushort* __restrict__ out, const int* __restrict__ rowptr,
    const int2* __restrict__ ew, const float* __restrict__ dis, int n) {
  int node = blockIdx.x * 4 + (threadIdx.x >> 6);
  if (node >= n) return;
  int lane = threadIdx.x & 63;
  int s = rowptr[node];
  int e = rowptr[node + 1];
  float ax = 0.f, ay = 0.f;
  int i = s;
  for (; i + 3 < e; i += 4) {
    int2 p0 = ew[i], p1 = ew[i + 1], p2 = ew[i + 2], p3 = ew[i + 3];
    uint v0 = *reinterpret_cast<const uint*>(in + ((size_t)p0.x << 7) + (lane << 1));
    uint v1 = *reinterpret_cast<const uint*>(in + ((size_t)p1.x << 7) + (lane << 1));
    uint v2 = *reinterpret_cast<const uint*>(in + ((size_t)p2.x << 7) + (lane << 1));
    uint v3 = *reinterpret_cast<const uint*>(in + ((size_t)p3.x << 7) + (lane << 1));
    float w0 = __builtin_bit_cast(float, p0.y);
    float w1 = __builtin_bit_cast(float, p1.y);
    float w2 = __builtin_bit_cast(float, p2.y);
    float w3 = __builtin_bit_cast(float, p3.y);
    ax = fmaf(w0, b2f((ushort)v0), ax);
    ay = fmaf(w0, b2f((ushort)(v0 >> 16)), ay);
    ax = fmaf(w1, b2f((ushort)v1), ax);
    ay = fmaf(w1, b2f((ushort)(v1 >> 16)), ay);
    ax = fmaf(w2, b2f((ushort)v2), ax);
    ay = fmaf(w2, b2f((ushort)(v2 >> 16)), ay);
    ax = fmaf(w3, b2f((ushort)v3), ax);
    ay = fmaf(w3, b2f((ushort)(v3 >> 16)), ay);
  }
  for (; i < e; ++i) {
    int2 p = ew[i];
    float w = __builtin_bit_cast(float, p.y);
    uint v = *reinterpret_cast<const uint*>(in + ((size_t)p.x << 7) + (lane << 1));
    ax = fmaf(w, b2f((ushort)v), ax);
    ay = fmaf(w, b2f((ushort)(v >> 16)), ay);
  }
  float sc = -dis[node];
  size_t ro = ((size_t)node << 7) + (lane << 1);
  float rx, ry;
  if (sub != nullptr) {
    uint sv = *reinterpret_cast<const uint*>(sub + ro);
    rx = fmaf(2.f * sc, ax, -b2f((ushort)sv));
    ry = fmaf(2.f * sc, ay, -b2f((ushort)(sv >> 16)));
  } else {
    rx = sc * ax;
    ry = sc * ay;
  }
  *reinterpret_cast<uint*>(out + ro) = (uint)f2b(rx) | ((uint)f2b(ry) << 16);
}

// ---------------- MFMA Chebyshev GEMM ----------------
// out = (relu?)( [A0|A1|A2|A3] @ packedW + bias ), A*: [n,128] bf16.
// One wave per 16 rows, no LDS. D mapping: col = lane&15, row = (lane>>4)*4 + reg.

template <int FOUT, bool RELU, bool OUT_BF16>
__global__ __launch_bounds__(256) void mfma_gemm_kernel(
    const ushort* __restrict__ A0, const ushort* __restrict__ A1,
    const ushort* __restrict__ A2, const ushort* __restrict__ A3,
    const ushort* __restrict__ pw, const float* __restrict__ bias,
    void* __restrict__ outv, int n) {
  constexpr int CT = FOUT / 16;
  int wid = threadIdx.x >> 6;
  int lane = threadIdx.x & 63;
  int row0 = (blockIdx.x * 4 + wid) * 16;
  if (row0 >= n) return;   // n % 16 == 0 for this problem
  const ushort* Ap[4] = {A0, A1, A2, A3};
  f32x4 acc[CT];
#pragma unroll
  for (int c = 0; c < CT; ++c) acc[c] = (f32x4){0.f, 0.f, 0.f, 0.f};
  size_t aoff = (size_t)(row0 + (lane & 15)) * 128 + (lane >> 4) * 8;
#pragma unroll
  for (int k = 0; k < 4; ++k) {
    const ushort* A = Ap[k] + aoff;
#pragma unroll
    for (int kk = 0; kk < 4; ++kk) {
      short8 a = *reinterpret_cast<const short8*>(A + kk * 32);
      const ushort* B = pw + ((size_t)((k * 4 + kk) * CT) * 64 + lane) * 8;
#pragma unroll
      for (int c = 0; c < CT; ++c) {
        short8 b = *reinterpret_cast<const short8*>(B + (size_t)c * 64 * 8);
        acc[c] = __builtin_amdgcn_mfma_f32_16x16x32_bf16(a, b, acc[c], 0, 0, 0);
      }
    }
  }
  int colb = lane & 15;
  int rsub = (lane >> 4) * 4;
#pragma unroll
  for (int c = 0; c < CT; ++c) {
    int col = c * 16 + colb;
    float bv = bias[col];
#pragma unroll
    for (int r = 0; r < 4; ++r) {
      float v = acc[c][r] + bv;
      if (RELU) v = fmaxf(v, 0.f);
      size_t oi = (size_t)(row0 + rsub + r) * FOUT + col;
      if (OUT_BF16) reinterpret_cast<ushort*>(outv)[oi] = f2b(v);
      else          reinterpret_cast<float*>(outv)[oi] = v;
    }
  }
}

// ---------------- row log-softmax (64 cols, one wave per row) ----------------

__global__ __launch_bounds__(256) void log_softmax_kernel(float* __restrict__ io, int n) {
  int row = blockIdx.x * 4 + (threadIdx.x >> 6);
  if (row >= n) return;
  int lane = threadIdx.x & 63;
  size_t idx = (size_t)row * 64 + lane;
  float v = io[idx];
  float m = v;
#pragma unroll
  for (int off = 32; off > 0; off >>= 1) m = fmaxf(m, __shfl_xor(m, off, 64));
  float ex = expf(v - m);
  float s = ex;
#pragma unroll
  for (int off = 32; off > 0; off >>= 1) s += __shfl_xor(s, off, 64);
  io[idx] = (v - m) - logf(s);
}

// ---------------- launcher ----------------

extern "C" void kernel_launch(void* const* d_in, const int* in_sizes, int n_in,
                              void* d_out, int out_size, void* d_ws, size_t ws_size,
                              hipStream_t stream) {
  const float* x  = (const float*)d_in[0];
  const int*   ei = (const int*)d_in[1];
  const float* W1 = (const float*)d_in[2];
  const float* b1 = (const float*)d_in[3];
  const float* W2 = (const float*)d_in[4];
  const float* b2 = (const float*)d_in[5];
  float* out = (float*)d_out;

  const int N = in_sizes[0] / N_IN;
  const int E = in_sizes[1] / 2;
  const int NB = (N + 255) / 256;

  char* base = (char*)d_ws;
  size_t off = 0;
  auto alloc = [&](size_t bytes) -> void* {
    void* p = base + off;
    off = (off + bytes + 255) & ~(size_t)255;
    return p;
  };
  int*    deg    = (int*)alloc((size_t)N * 4);
  int*    rowptr = (int*)alloc((size_t)(N + 1) * 4);
  int*    cursor = (int*)alloc((size_t)N * 4);
  int*    bsum   = (int*)alloc((size_t)NB * 4);
  int2*   ew     = (int2*)alloc((size_t)E * 8);
  float*  dis    = (float*)alloc((size_t)N * 4);
  ushort* xb     = (ushort*)alloc((size_t)N * N_IN * 2);
  ushort* T1     = (ushort*)alloc((size_t)N * N_IN * 2);
  ushort* T2     = (ushort*)alloc((size_t)N * N_IN * 2);
  ushort* T3     = (ushort*)alloc((size_t)N * N_IN * 2);
  ushort* H      = (ushort*)alloc((size_t)N * N_IN * 2);
  ushort* pw1    = (ushort*)alloc((size_t)4 * N_IN * N_HID * 2);
  ushort* pw2    = (ushort*)alloc((size_t)4 * N_HID * N_OUT * 2);

  hipMemsetAsync(deg, 0, (size_t)N * 4, stream);
  count_deg_kernel<<<(E + 255) / 256, 256, 0, stream>>>(ei, deg, E);
  scanA_kernel<<<NB, 256, 0, stream>>>(deg, bsum, N);
  scanB_kernel<<<1, 256, 0, stream>>>(bsum, NB);
  scanC_kernel<<<NB, 256, 0, stream>>>(deg, bsum, rowptr, dis, N);
  hipMemcpyAsync(cursor, rowptr, (size_t)N * 4, hipMemcpyDeviceToDevice, stream);
  fill_csr_kernel<<<(E + 255) / 256, 256, 0, stream>>>(ei, cursor, ew, dis, E);

  int n4 = N * N_IN / 4;
  cvt_bf16_kernel<<<(n4 + 255) / 256, 256, 0, stream>>>(x, xb, n4);
  pack_w_kernel<N_HID><<<(4 * 4 * (N_HID / 16) * 64 + 255) / 256, 256, 0, stream>>>(W1, pw1);
  pack_w_kernel<N_OUT><<<(4 * 4 * (N_OUT / 16) * 64 + 255) / 256, 256, 0, stream>>>(W2, pw2);

  int pgrid = (N + 3) / 4;
  int ggrid = (N + 63) / 64;
  // layer 1: Tx0 = xb
  prop_kernel<<<pgrid, 256, 0, stream>>>(xb, nullptr, T1, rowptr, ew, dis, N);
  prop_kernel<<<pgrid, 256, 0, stream>>>(T1, xb,      T2, rowptr, ew, dis, N);
  prop_kernel<<<pgrid, 256, 0, stream>>>(T2, T1,      T3, rowptr, ew, dis, N);
  mfma_gemm_kernel<N_HID, true, true><<<ggrid, 256, 0, stream>>>(xb, T1, T2, T3, pw1, b1, H, N);
  // layer 2: Tx0 = H
  prop_kernel<<<pgrid, 256, 0, stream>>>(H,  nullptr, T1, rowptr, ew, dis, N);
  prop_kernel<<<pgrid, 256, 0, stream>>>(T1, H,       T2, rowptr, ew, dis, N);
  prop_kernel<<<pgrid, 256, 0, stream>>>(T2, T1,      T3, rowptr, ew, dis, N);
  mfma_gemm_kernel<N_OUT, false, false><<<ggrid, 256, 0, stream>>>(H, T1, T2, T3, pw2, b2, out, N);

  log_softmax_kernel<<<(N + 3) / 4, 256, 0, stream>>>(out, N);
}

// Round 4
// 370.150 us; speedup vs baseline: 2.5565x; 1.1005x over previous
//
#include <hip/hip_runtime.h>
#include <cstddef>
#include <cstdint>

#define N_IN  128
#define N_HID 128
#define N_OUT 64

typedef unsigned short ushort;
typedef unsigned int uint;
using short8 = __attribute__((ext_vector_type(8))) short;
using f32x4  = __attribute__((ext_vector_type(4))) float;

__device__ __forceinline__ ushort f2b(float f) {
  uint u = __builtin_bit_cast(uint, f);
  uint r = (u + 0x7fffu + ((u >> 16) & 1u)) >> 16;   // RNE
  return (ushort)r;
}
__device__ __forceinline__ float b2f(ushort u) {
  return __builtin_bit_cast(float, ((uint)u) << 16);
}

// ---------------- CSR build ----------------

__global__ void count_deg_kernel(const int* __restrict__ ei, int* __restrict__ deg, int E) {
  int e = blockIdx.x * 256 + threadIdx.x;
  if (e < E) atomicAdd(&deg[ei[E + e]], 1);
}

__global__ __launch_bounds__(256) void scanA_kernel(const int* __restrict__ deg,
                                                    int* __restrict__ bsum, int n) {
  int i = blockIdx.x * 256 + threadIdx.x;
  int v = (i < n) ? deg[i] : 0;
#pragma unroll
  for (int off = 32; off > 0; off >>= 1) v += __shfl_xor(v, off, 64);
  __shared__ int ws[4];
  int lane = threadIdx.x & 63, wid = threadIdx.x >> 6;
  if (lane == 0) ws[wid] = v;
  __syncthreads();
  if (threadIdx.x == 0) bsum[blockIdx.x] = ws[0] + ws[1] + ws[2] + ws[3];
}

__global__ __launch_bounds__(256) void scanB_kernel(int* __restrict__ bsum, int nb) {
  int tid = threadIdx.x;
  int c = (nb + 255) >> 8;
  int st = tid * c, en = min(st + c, nb);
  int s = 0;
  for (int i = st; i < en; ++i) s += bsum[i];
  int lane = tid & 63, wid = tid >> 6;
  int incl = s;
#pragma unroll
  for (int off = 1; off < 64; off <<= 1) {
    int t = __shfl_up(incl, off, 64);
    if (lane >= off) incl += t;
  }
  __shared__ int ws[4];
  if (lane == 63) ws[wid] = incl;
  __syncthreads();
  int wbase = 0;
  for (int w = 0; w < wid; ++w) wbase += ws[w];
  int ex = wbase + incl - s;
  for (int i = st; i < en; ++i) {
    int d = bsum[i];
    bsum[i] = ex;
    ex += d;
  }
}

__global__ __launch_bounds__(256) void scanC_kernel(const int* __restrict__ deg,
                                                    const int* __restrict__ bsum,
                                                    int* __restrict__ rowptr,
                                                    float* __restrict__ dis, int n) {
  int i = blockIdx.x * 256 + threadIdx.x;
  int d = (i < n) ? deg[i] : 0;
  int lane = threadIdx.x & 63, wid = threadIdx.x >> 6;
  int incl = d;
#pragma unroll
  for (int off = 1; off < 64; off <<= 1) {
    int t = __shfl_up(incl, off, 64);
    if (lane >= off) incl += t;
  }
  __shared__ int ws[4];
  if (lane == 63) ws[wid] = incl;
  __syncthreads();
  int wbase = 0;
  for (int w = 0; w < wid; ++w) wbase += ws[w];
  int ex = bsum[blockIdx.x] + wbase + incl - d;
  if (i < n) {
    rowptr[i] = ex;
    dis[i] = (d > 0) ? rsqrtf((float)d) : 0.0f;
    if (i == n - 1) rowptr[n] = ex + d;
  }
}

// colidx-only fill: weights are folded into scaled features
__global__ void fill_csr_kernel(const int* __restrict__ ei, int* __restrict__ cursor,
                                int* __restrict__ colidx, int E) {
  int e = blockIdx.x * 256 + threadIdx.x;
  if (e >= E) return;
  int s = ei[e];
  int d = ei[E + e];
  int pos = atomicAdd(&cursor[d], 1);
  colidx[pos] = s;
}

// ---------------- fp32 -> bf16 convert (plain + dis-scaled copies) ----------------

__global__ __launch_bounds__(256) void cvt_bf16_kernel(const float* __restrict__ in,
                                                       ushort* __restrict__ xb,
                                                       ushort* __restrict__ xs,
                                                       const float* __restrict__ dis, int n4) {
  int i = blockIdx.x * 256 + threadIdx.x;
  if (i >= n4) return;
  float4 v = reinterpret_cast<const float4*>(in)[i];
  float d = dis[i >> 5];   // 32 float4 per 128-wide row
  ushort4 o, os;
  o.x = f2b(v.x); o.y = f2b(v.y); o.z = f2b(v.z); o.w = f2b(v.w);
  os.x = f2b(v.x * d); os.y = f2b(v.y * d); os.z = f2b(v.z * d); os.w = f2b(v.w * d);
  reinterpret_cast<ushort4*>(xb)[i] = o;
  reinterpret_cast<ushort4*>(xs)[i] = os;
}

// ---------------- W pack into MFMA B-fragment order ----------------
// pw[(k*4+kk)*CT + ct][lane][j] = W[k][kk*32 + (lane>>4)*8 + j][ct*16 + (lane&15)]

template <int FOUT>
__global__ __launch_bounds__(256) void pack_w_kernel(const float* __restrict__ W,
                                                     ushort* __restrict__ pw) {
  constexpr int CT = FOUT / 16;
  int t = blockIdx.x * 256 + threadIdx.x;
  if (t >= 4 * 4 * CT * 64) return;
  int lane = t & 63;
  int g = t >> 6;
  int ct = g % CT;
  int kk = (g / CT) % 4;
  int k  = g / (CT * 4);
  int col = ct * 16 + (lane & 15);
  int krow0 = kk * 32 + (lane >> 4) * 8;
  ushort* dst = pw + (size_t)t * 8;
  const float* src = W + ((size_t)k * 128 + krow0) * FOUT + col;
#pragma unroll
  for (int j = 0; j < 8; ++j) dst[j] = f2b(src[(size_t)j * FOUT]);
}

// ---------------- sparse propagation ----------------
// ins = dis-scaled input features (bf16). s_i = sum_{e in row} ins[src_e]
// out_i  = -dis_i * s_i                (sub == nullptr)
// out_i  = 2*(-dis_i*s_i) - sub_i      (sub != nullptr)
// outs_i = dis_i * out_i   (scaled copy for the next prop; optional)
// one wave per node; unroll x8 -> 8 outstanding 256B gathers

__global__ __launch_bounds__(256) void prop_kernel(
    const ushort* __restrict__ ins, const ushort* __restrict__ sub,
    ushort* __restrict__ out, ushort* __restrict__ outs,
    const int* __restrict__ rowptr, const int* __restrict__ colidx,
    const float* __restrict__ dis, int n) {
  int node = blockIdx.x * 4 + (threadIdx.x >> 6);
  if (node >= n) return;
  int lane = threadIdx.x & 63;
  int s = rowptr[node];
  int e = rowptr[node + 1];
  size_t ro = ((size_t)node << 7) + (lane << 1);
  uint sv = 0;
  if (sub != nullptr) sv = *reinterpret_cast<const uint*>(sub + ro);
  float ax = 0.f, ay = 0.f;
  int i = s;
  for (; i + 8 <= e; i += 8) {
    int c[8];
#pragma unroll
    for (int j = 0; j < 8; ++j) c[j] = colidx[i + j];
    uint v[8];
#pragma unroll
    for (int j = 0; j < 8; ++j)
      v[j] = *reinterpret_cast<const uint*>(ins + ((size_t)c[j] << 7) + (lane << 1));
#pragma unroll
    for (int j = 0; j < 8; ++j) {
      ax += b2f((ushort)v[j]);
      ay += b2f((ushort)(v[j] >> 16));
    }
  }
  if (i + 4 <= e) {
    int c[4];
#pragma unroll
    for (int j = 0; j < 4; ++j) c[j] = colidx[i + j];
    uint v[4];
#pragma unroll
    for (int j = 0; j < 4; ++j)
      v[j] = *reinterpret_cast<const uint*>(ins + ((size_t)c[j] << 7) + (lane << 1));
#pragma unroll
    for (int j = 0; j < 4; ++j) {
      ax += b2f((ushort)v[j]);
      ay += b2f((ushort)(v[j] >> 16));
    }
    i += 4;
  }
  for (; i < e; ++i) {
    uint v = *reinterpret_cast<const uint*>(ins + ((size_t)colidx[i] << 7) + (lane << 1));
    ax += b2f((ushort)v);
    ay += b2f((ushort)(v >> 16));
  }
  float dn = dis[node];
  float sc = -dn;
  float rx, ry;
  if (sub != nullptr) {
    rx = fmaf(2.f * sc, ax, -b2f((ushort)sv));
    ry = fmaf(2.f * sc, ay, -b2f((ushort)(sv >> 16)));
  } else {
    rx = sc * ax;
    ry = sc * ay;
  }
  *reinterpret_cast<uint*>(out + ro) = (uint)f2b(rx) | ((uint)f2b(ry) << 16);
  if (outs != nullptr)
    *reinterpret_cast<uint*>(outs + ro) = (uint)f2b(rx * dn) | ((uint)f2b(ry * dn) << 16);
}

// ---------------- MFMA Chebyshev GEMM ----------------
// out = epilogue( [A0|A1|A2|A3] @ packedW + bias ), A*: [n,128] bf16.
// 2 waves/block, each wave does 2 row-tiles of 16 (32 rows) -> B-frag reused 2x.
// D mapping: col = lane&15, row = (lane>>4)*4 + reg.
// FUSE_LSM (FOUT=64 only): wave holds full 64-col rows; log-softmax in-register.

template <int FOUT, bool RELU, bool OUT_BF16, bool WRITE_SCALED, bool FUSE_LSM>
__global__ __launch_bounds__(128) void mfma_gemm_kernel(
    const ushort* __restrict__ A0, const ushort* __restrict__ A1,
    const ushort* __restrict__ A2, const ushort* __restrict__ A3,
    const ushort* __restrict__ pw, const float* __restrict__ bias,
    void* __restrict__ outv, ushort* __restrict__ outs,
    const float* __restrict__ dis, int n) {
  constexpr int CT = FOUT / 16;
  int wid = threadIdx.x >> 6;
  int lane = threadIdx.x & 63;
  int rbase = (blockIdx.x * 2 + wid) * 32;
  if (rbase >= n) return;                 // n % 16 == 0
  bool t1ok = (rbase + 16) < n;
  const ushort* Ap[4] = {A0, A1, A2, A3};
  f32x4 acc[2][CT];
#pragma unroll
  for (int t = 0; t < 2; ++t)
#pragma unroll
    for (int c = 0; c < CT; ++c) acc[t][c] = (f32x4){0.f, 0.f, 0.f, 0.f};
  size_t aoff = (size_t)(rbase + (lane & 15)) * 128 + (lane >> 4) * 8;
#pragma unroll
  for (int k = 0; k < 4; ++k) {
    const ushort* A = Ap[k] + aoff;
#pragma unroll
    for (int kk = 0; kk < 4; ++kk) {
      short8 a0 = *reinterpret_cast<const short8*>(A + kk * 32);
      short8 a1 = {};
      if (t1ok) a1 = *reinterpret_cast<const short8*>(A + 16 * 128 + kk * 32);
      const ushort* B = pw + ((size_t)((k * 4 + kk) * CT) * 64 + lane) * 8;
#pragma unroll
      for (int c = 0; c < CT; ++c) {
        short8 b = *reinterpret_cast<const short8*>(B + (size_t)c * 64 * 8);
        acc[0][c] = __builtin_amdgcn_mfma_f32_16x16x32_bf16(a0, b, acc[0][c], 0, 0, 0);
        acc[1][c] = __builtin_amdgcn_mfma_f32_16x16x32_bf16(a1, b, acc[1][c], 0, 0, 0);
      }
    }
  }
  int colb = lane & 15;
  int rsub = (lane >> 4) * 4;
#pragma unroll
  for (int t = 0; t < 2; ++t) {
    int row0 = rbase + t * 16;
    if (row0 >= n) continue;
    if (FUSE_LSM) {
      // full row (64 cols) lives in 16 lanes x CT regs for each r
#pragma unroll
      for (int r = 0; r < 4; ++r) {
        int row = row0 + rsub + r;
        float v[CT];
        float m = -1e30f;
#pragma unroll
        for (int c = 0; c < CT; ++c) {
          v[c] = acc[t][c][r] + bias[c * 16 + colb];
          m = fmaxf(m, v[c]);
        }
#pragma unroll
        for (int off = 1; off < 16; off <<= 1) m = fmaxf(m, __shfl_xor(m, off, 64));
        float s = 0.f;
#pragma unroll
        for (int c = 0; c < CT; ++c) s += __expf(v[c] - m);
#pragma unroll
        for (int off = 1; off < 16; off <<= 1) s += __shfl_xor(s, off, 64);
        float ls = logf(s) + m;
#pragma unroll
        for (int c = 0; c < CT; ++c)
          reinterpret_cast<float*>(outv)[(size_t)row * FOUT + c * 16 + colb] = v[c] - ls;
      }
    } else {
#pragma unroll
      for (int c = 0; c < CT; ++c) {
        int col = c * 16 + colb;
        float bv = bias[col];
#pragma unroll
        for (int r = 0; r < 4; ++r) {
          int row = row0 + rsub + r;
          float v = acc[t][c][r] + bv;
          if (RELU) v = fmaxf(v, 0.f);
          size_t oi = (size_t)row * FOUT + col;
          if (OUT_BF16) reinterpret_cast<ushort*>(outv)[oi] = f2b(v);
          else          reinterpret_cast<float*>(outv)[oi] = v;
          if (WRITE_SCALED) outs[oi] = f2b(v * dis[row]);
        }
      }
    }
  }
}

// ---------------- launcher ----------------

extern "C" void kernel_launch(void* const* d_in, const int* in_sizes, int n_in,
                              void* d_out, int out_size, void* d_ws, size_t ws_size,
                              hipStream_t stream) {
  const float* x  = (const float*)d_in[0];
  const int*   ei = (const int*)d_in[1];
  const float* W1 = (const float*)d_in[2];
  const float* b1 = (const float*)d_in[3];
  const float* W2 = (const float*)d_in[4];
  const float* b2 = (const float*)d_in[5];
  float* out = (float*)d_out;

  const int N = in_sizes[0] / N_IN;
  const int E = in_sizes[1] / 2;
  const int NB = (N + 255) / 256;

  char* base = (char*)d_ws;
  size_t off = 0;
  auto alloc = [&](size_t bytes) -> void* {
    void* p = base + off;
    off = (off + bytes + 255) & ~(size_t)255;
    return p;
  };
  int*    deg    = (int*)alloc((size_t)N * 4);
  int*    rowptr = (int*)alloc((size_t)(N + 1) * 4);
  int*    cursor = (int*)alloc((size_t)N * 4);
  int*    bsum   = (int*)alloc((size_t)NB * 4);
  int*    colidx = (int*)alloc((size_t)E * 4);
  float*  dis    = (float*)alloc((size_t)N * 4);
  size_t  fsz    = (size_t)N * N_IN * 2;
  ushort* S1 = (ushort*)alloc(fsz);
  ushort* S2 = (ushort*)alloc(fsz);
  ushort* S3 = (ushort*)alloc(fsz);
  ushort* S4 = (ushort*)alloc(fsz);
  ushort* S5 = (ushort*)alloc(fsz);
  ushort* S6 = (ushort*)alloc(fsz);
  ushort* pw1 = (ushort*)alloc((size_t)4 * N_IN * N_HID * 2);
  ushort* pw2 = (ushort*)alloc((size_t)4 * N_HID * N_OUT * 2);

  // buffer aliases (lifetime-disjoint, stream-ordered)
  ushort *xb = S1, *xs = S2, *T1 = S3, *T1s = S4, *T2 = S5;
  ushort *T2s = S2, *T3 = S4;                 // xs dead after prop1, T1s after prop2
  ushort *H = S6, *Hs = S2;                   // T2s dead after prop3
  ushort *U1 = S1, *U1s = S3, *U2 = S4, *U2s = S5, *U3 = S3;

  hipMemsetAsync(deg, 0, (size_t)N * 4, stream);
  count_deg_kernel<<<(E + 255) / 256, 256, 0, stream>>>(ei, deg, E);
  scanA_kernel<<<NB, 256, 0, stream>>>(deg, bsum, N);
  scanB_kernel<<<1, 256, 0, stream>>>(bsum, NB);
  scanC_kernel<<<NB, 256, 0, stream>>>(deg, bsum, rowptr, dis, N);
  hipMemcpyAsync(cursor, rowptr, (size_t)N * 4, hipMemcpyDeviceToDevice, stream);
  fill_csr_kernel<<<(E + 255) / 256, 256, 0, stream>>>(ei, cursor, colidx, E);

  int n4 = N * N_IN / 4;
  cvt_bf16_kernel<<<(n4 + 255) / 256, 256, 0, stream>>>(x, xb, xs, dis, n4);
  pack_w_kernel<N_HID><<<(4 * 4 * (N_HID / 16) * 64 + 255) / 256, 256, 0, stream>>>(W1, pw1);
  pack_w_kernel<N_OUT><<<(4 * 4 * (N_OUT / 16) * 64 + 255) / 256, 256, 0, stream>>>(W2, pw2);

  int pgrid = (N + 3) / 4;
  int ggrid = (N + 63) / 64;
  // layer 1: Tx0 = x
  prop_kernel<<<pgrid, 256, 0, stream>>>(xs,  nullptr, T1, T1s, rowptr, colidx, dis, N);
  prop_kernel<<<pgrid, 256, 0, stream>>>(T1s, xb,      T2, T2s, rowptr, colidx, dis, N);
  prop_kernel<<<pgrid, 256, 0, stream>>>(T2s, T1,      T3, nullptr, rowptr, colidx, dis, N);
  mfma_gemm_kernel<N_HID, true, true, true, false><<<ggrid, 128, 0, stream>>>(
      xb, T1, T2, T3, pw1, b1, H, Hs, dis, N);
  // layer 2: Tx0 = H
  prop_kernel<<<pgrid, 256, 0, stream>>>(Hs,  nullptr, U1, U1s, rowptr, colidx, dis, N);
  prop_kernel<<<pgrid, 256, 0, stream>>>(U1s, H,       U2, U2s, rowptr, colidx, dis, N);
  prop_kernel<<<pgrid, 256, 0, stream>>>(U2s, U1,      U3, nullptr, rowptr, colidx, dis, N);
  mfma_gemm_kernel<N_OUT, false, false, false, true><<<ggrid, 128, 0, stream>>>(
      H, U1, U2, U3, pw2, b2, out, nullptr, dis, N);
}